// Round 1
// baseline (130.699 us; speedup 1.0000x reference)
//
#include <hip/hip_runtime.h>
#include <stdint.h>

#define BS   16384
#define XRW  768
#define HD   256
#define DIN  1280
#define N4   1024
#define NKT  20   // 1280 / 64

typedef __attribute__((ext_vector_type(4))) float f32x4;
typedef __attribute__((ext_vector_type(4))) short s16x4;
typedef __attribute__((ext_vector_type(8))) short s16x8;

__device__ __forceinline__ unsigned short f2bf(float f) {
  uint32_t u = __builtin_bit_cast(uint32_t, f);
  u += 0x7FFFu + ((u >> 16) & 1u);   // RNE, matches v_cvt_pk_bf16 semantics
  return (unsigned short)(u >> 16);
}

__device__ __forceinline__ float sigmoidf_(float x) {
  return 1.0f / (1.0f + __expf(-x));
}
__device__ __forceinline__ float tanhf_(float x) {
  return 1.0f - 2.0f / (__expf(2.0f * x) + 1.0f);
}

// Build Wt[n'][k] (bf16, n' = h*4 + gate) and b4[n'] from the four gate weights.
// Reads coalesced along h (256 consecutive f32); writes scattered but W is only
// 5.2 MB total -> L2/L3 absorbs.
__global__ void conv_w_kernel(const float* __restrict__ Wi, const float* __restrict__ bi,
                              const float* __restrict__ Wf, const float* __restrict__ bfv,
                              const float* __restrict__ Wo, const float* __restrict__ bo,
                              const float* __restrict__ Ws, const float* __restrict__ bsv,
                              unsigned short* __restrict__ Wt, float* __restrict__ b4) {
  const int np = blockIdx.x;            // n' in [0,1024)
  const int h = np >> 2, g = np & 3;
  const float* W  = (g == 0) ? Wi : (g == 1) ? Wf : (g == 2) ? Wo : Ws;
  const float* bb = (g == 0) ? bi : (g == 1) ? bfv : (g == 2) ? bo : bsv;
  if (threadIdx.x == 0) b4[np] = bb[h];
  for (int k = threadIdx.x; k < DIN; k += 256)
    Wt[np * DIN + k] = f2bf(W[k * HD + h]);
}

// 128x128 tile, BK=64, 4 waves (2x2 of 64x64), mfma_f32_16x16x32_bf16.
// A = concat(x, pt, pl) loaded f32 -> bf16 in regs -> swizzled LDS.
// B = Wt rows (already bf16) -> swizzled LDS.
// Epilogue fuses bias + sigmoid/tanh gating, writes new_hidden & new_state.
__launch_bounds__(256, 2)
__global__ void lstm_gemm_kernel(const float* __restrict__ X,
                                 const float* __restrict__ PT,
                                 const float* __restrict__ PL,
                                 const float* __restrict__ OLD,
                                 const unsigned short* __restrict__ Wt,
                                 const float* __restrict__ b4,
                                 float* __restrict__ out) {
  __shared__ unsigned char smem[32768];   // A: [0,16K) B: [16K,32K), both [128][64] bf16 swizzled
  const int tid  = threadIdx.x;
  const int wid  = tid >> 6;
  const int lane = tid & 63;
  const int bid  = blockIdx.x;
  const int nt   = bid & 7;     // 8 N-tiles of 128 (gate-interleaved columns)
  const int mt   = bid >> 3;    // 128 M-tiles
  const int wr   = wid >> 1, wc = wid & 1;

  f32x4 acc[4][4];
  #pragma unroll
  for (int i = 0; i < 4; ++i)
    #pragma unroll
    for (int j = 0; j < 4; ++j) {
      f32x4 z = {0.0f, 0.0f, 0.0f, 0.0f};
      acc[i][j] = z;
    }

  for (int kt = 0; kt < NKT; ++kt) {
    // ---- source for this K-tile (wave-uniform; 768 and 1024 are BK-aligned)
    const float* asrc; int astr, aoff;
    if (kt < 12)      { asrc = X;  astr = XRW; aoff = kt * 64; }
    else if (kt < 16) { asrc = PT; astr = HD;  aoff = (kt - 12) * 64; }
    else              { asrc = PL; astr = HD;  aoff = (kt - 16) * 64; }

    // ---- stage A: 128x64 f32 -> bf16, XOR-swizzled
    #pragma unroll
    for (int i = 0; i < 8; ++i) {
      const int idx = tid + i * 256;
      const int row = idx >> 4;
      const int c4  = (idx & 15) << 2;
      f32x4 v = *(const f32x4*)(asrc + (size_t)(mt * 128 + row) * astr + aoff + c4);
      s16x4 sv;
      sv.x = (short)f2bf(v.x); sv.y = (short)f2bf(v.y);
      sv.z = (short)f2bf(v.z); sv.w = (short)f2bf(v.w);
      int byte_ = (row << 7) + (c4 << 1);
      byte_ ^= (row & 7) << 4;
      *(s16x4*)(&smem[byte_]) = sv;
    }
    // ---- stage B: 128x64 bf16, XOR-swizzled
    #pragma unroll
    for (int i = 0; i < 4; ++i) {
      const int idx = tid + i * 256;
      const int row = idx >> 3;
      const int c8  = (idx & 7) << 3;
      s16x8 v = *(const s16x8*)(Wt + (size_t)(nt * 128 + row) * DIN + kt * 64 + c8);
      int byte_ = 16384 + (row << 7) + (c8 << 1);
      byte_ ^= (row & 7) << 4;
      *(s16x8*)(&smem[byte_]) = v;
    }
    __syncthreads();

    // ---- compute: 2 k-halves x 4x4 fragments
    #pragma unroll
    for (int kh = 0; kh < 2; ++kh) {
      s16x8 aq[4], bq[4];
      #pragma unroll
      for (int mf = 0; mf < 4; ++mf) {
        const int row = wr * 64 + mf * 16 + (lane & 15);
        int byte_ = (row << 7) + ((kh * 32 + (lane >> 4) * 8) << 1);
        byte_ ^= (row & 7) << 4;
        aq[mf] = *(s16x8*)(&smem[byte_]);
      }
      #pragma unroll
      for (int nf = 0; nf < 4; ++nf) {
        const int row = wc * 64 + nf * 16 + (lane & 15);
        int byte_ = 16384 + (row << 7) + ((kh * 32 + (lane >> 4) * 8) << 1);
        byte_ ^= (row & 7) << 4;
        bq[nf] = *(s16x8*)(&smem[byte_]);
      }
      #pragma unroll
      for (int mf = 0; mf < 4; ++mf)
        #pragma unroll
        for (int nf = 0; nf < 4; ++nf)
          acc[mf][nf] = __builtin_amdgcn_mfma_f32_16x16x32_bf16(aq[mf], bq[nf], acc[mf][nf], 0, 0, 0);
    }
    __syncthreads();
  }

  // ---- fused epilogue. Each wave's 64 columns are 16 complete gate quads
  // (n' = h*4+g), so no cross-wave traffic. 2 passes of 32 rows to fit 8KB/wave.
  __syncthreads();
  float* creg = (float*)smem + wid * 2048;   // [32][64] f32 per wave
  const int mbase = mt * 128 + wr * 64;
  const int hbase = nt * 32 + wc * 16;
  const int bcol  = nt * 128 + wc * 64;
  #pragma unroll
  for (int p = 0; p < 2; ++p) {
    #pragma unroll
    for (int mf = 0; mf < 2; ++mf) {
      #pragma unroll
      for (int nf = 0; nf < 4; ++nf) {
        const int lrow = mf * 16 + (lane >> 4) * 4;   // C/D: row=(lane>>4)*4+r
        const int lcol = nf * 16 + (lane & 15);       //      col=lane&15
        #pragma unroll
        for (int r = 0; r < 4; ++r)
          creg[(lrow + r) * 64 + lcol] = acc[p * 2 + mf][nf][r];
      }
    }
    #pragma unroll
    for (int j = 0; j < 8; ++j) {
      const int idx = lane + j * 64;
      const int row = idx >> 4;
      const int hc  = idx & 15;
      f32x4 g4 = *(f32x4*)(creg + row * 64 + hc * 4);
      f32x4 bb = *(const f32x4*)(b4 + bcol + hc * 4);
      const int m  = mbase + p * 32 + row;
      const int hg = hbase + hc;
      const float ig = sigmoidf_(g4.x + bb.x);
      const float fg = sigmoidf_(g4.y + bb.y);
      const float og = sigmoidf_(g4.z + bb.z);
      const float cg = tanhf_(g4.w + bb.w);
      const float ns = fg * OLD[m * HD + hg] + ig * cg;
      const float nh = og * tanhf_(ns);
      out[m * HD + hg] = nh;
      out[BS * HD + m * HD + hg] = ns;
    }
  }
}

extern "C" void kernel_launch(void* const* d_in, const int* in_sizes, int n_in,
                              void* d_out, int out_size, void* d_ws, size_t ws_size,
                              hipStream_t stream) {
  const float* X   = (const float*)d_in[0];
  const float* PT  = (const float*)d_in[1];
  const float* PL  = (const float*)d_in[2];
  const float* OLD = (const float*)d_in[3];
  const float* Wi  = (const float*)d_in[4];
  const float* bi  = (const float*)d_in[5];
  const float* Wf  = (const float*)d_in[6];
  const float* bfv = (const float*)d_in[7];
  const float* Wo  = (const float*)d_in[8];
  const float* bo  = (const float*)d_in[9];
  const float* Ws  = (const float*)d_in[10];
  const float* bsv = (const float*)d_in[11];
  float* out = (float*)d_out;

  unsigned short* Wt = (unsigned short*)d_ws;                       // 1024*1280*2 = 2.62 MB
  float* b4 = (float*)((char*)d_ws + (size_t)N4 * DIN * 2);         // + 4 KB

  conv_w_kernel<<<N4, 256, 0, stream>>>(Wi, bi, Wf, bfv, Wo, bo, Ws, bsv, Wt, b4);
  lstm_gemm_kernel<<<(BS / 128) * 8, 256, 0, stream>>>(X, PT, PL, OLD, Wt, b4, out);
}

// Round 2
// 82.258 us; speedup vs baseline: 1.5889x; 1.5889x over previous
//
#include <hip/hip_runtime.h>
#include <stdint.h>

#define BS   16384
#define XRW  768
#define HD   256
#define DIN  1280
#define N4   1024
#define NKT  20   // 1280 / 64

typedef __attribute__((ext_vector_type(4))) float f32x4;
typedef __attribute__((ext_vector_type(4))) short s16x4;
typedef __attribute__((ext_vector_type(8))) short s16x8;

__device__ __forceinline__ unsigned short f2bf(float f) {
  uint32_t u = __builtin_bit_cast(uint32_t, f);
  u += 0x7FFFu + ((u >> 16) & 1u);   // RNE
  return (unsigned short)(u >> 16);
}

__device__ __forceinline__ float sigmoidf_(float x) {
  return 1.0f / (1.0f + __expf(-x));
}
__device__ __forceinline__ float tanhf_(float x) {
  return 1.0f - 2.0f / (__expf(2.0f * x) + 1.0f);
}

__device__ __forceinline__ void gload16(const void* g, void* l) {
  __builtin_amdgcn_global_load_lds((const __attribute__((address_space(1))) void*)g,
                                   (__attribute__((address_space(3))) void*)l, 16, 0, 0);
}

// ---- Wt[n'][k] bf16 row-major, n' = h*4 + gate; b4[n'].
__global__ void conv_w_kernel(const float* __restrict__ Wi, const float* __restrict__ bi,
                              const float* __restrict__ Wf, const float* __restrict__ bfv,
                              const float* __restrict__ Wo, const float* __restrict__ bo,
                              const float* __restrict__ Ws, const float* __restrict__ bsv,
                              unsigned short* __restrict__ Wt, float* __restrict__ b4) {
  const int np = blockIdx.x;
  const int h = np >> 2, g = np & 3;
  const float* W  = (g == 0) ? Wi : (g == 1) ? Wf : (g == 2) ? Wo : Ws;
  const float* bb = (g == 0) ? bi : (g == 1) ? bfv : (g == 2) ? bo : bsv;
  if (threadIdx.x == 0) b4[np] = bb[h];
  for (int k = threadIdx.x; k < DIN; k += 256)
    Wt[np * DIN + k] = f2bf(W[k * HD + h]);
}

// ---- Abf[m][k] bf16 row-major = concat(x, pt, pl) converted. Memory-bound.
__global__ __launch_bounds__(256) void conv_a_kernel(const float* __restrict__ X,
                                                     const float* __restrict__ PT,
                                                     const float* __restrict__ PL,
                                                     unsigned short* __restrict__ Abf) {
  const int idx = blockIdx.x * 256 + threadIdx.x;   // [0, 16384*160)
  const int m = idx / 160;
  const int c = idx - m * 160;
  const int k = c << 3;
  const float* src;
  if (k < XRW)           src = X  + (size_t)m * XRW + k;
  else if (k < XRW + HD) src = PT + (size_t)m * HD + (k - XRW);
  else                   src = PL + (size_t)m * HD + (k - XRW - HD);
  f32x4 a = *(const f32x4*)src;
  f32x4 b = *(const f32x4*)(src + 4);
  s16x8 o;
  o[0] = (short)f2bf(a.x); o[1] = (short)f2bf(a.y);
  o[2] = (short)f2bf(a.z); o[3] = (short)f2bf(a.w);
  o[4] = (short)f2bf(b.x); o[5] = (short)f2bf(b.y);
  o[6] = (short)f2bf(b.z); o[7] = (short)f2bf(b.w);
  *(s16x8*)(Abf + (size_t)idx * 8) = o;
}

// ---- 128x128 tile, BK=64, 4 waves (2x2 of 64x64), mfma_f32_16x16x32_bf16.
// Both operands staged via global_load_lds w=16 (linear LDS dest, pre-swizzled
// per-lane global source); ds_read uses the XOR swizzle. Fused gate epilogue.
__global__ __launch_bounds__(256, 4)
void lstm_gemm_kernel(const unsigned short* __restrict__ Abf,
                      const unsigned short* __restrict__ Wt,
                      const float* __restrict__ b4,
                      const float* __restrict__ OLD,
                      float* __restrict__ out) {
  __shared__ unsigned char smem[32768];   // A: [0,16K) B: [16K,32K)
  const int tid  = threadIdx.x;
  const int wid  = tid >> 6;
  const int lane = tid & 63;

  // XCD grouping: all 8 nt of one mt land on the same XCD (A-panel L2 reuse)
  const int H = blockIdx.x;
  const int xcd = H & 7, slot = H >> 3;
  const int mt = xcd * 16 + (slot >> 3);
  const int nt = slot & 7;
  const int wr = wid >> 1, wc = wid & 1;

  // Staging geometry: LDS slot p = wid*4096 + c*1024 + lane*16
  //   row(p) = wid*32 + c*8 + (lane>>3);  row&7 == lane>>3  (loop-invariant!)
  //   logical colbyte = (p&127) ^ ((row&7)<<4) = ((lane&7) ^ (lane>>3))<<4
  const int r8 = lane >> 3;
  const int colbyte = ((lane & 7) ^ r8) << 4;
  const char* gA = (const char*)Abf + (size_t)(mt * 128 + wid * 32 + r8) * (DIN * 2) + colbyte;
  const char* gB = (const char*)Wt  + (size_t)(nt * 128 + wid * 32 + r8) * (DIN * 2) + colbyte;
  unsigned char* ldsA = &smem[wid * 4096];
  unsigned char* ldsB = &smem[16384 + wid * 4096];

  f32x4 acc[4][4];
  #pragma unroll
  for (int i = 0; i < 4; ++i)
    #pragma unroll
    for (int j = 0; j < 4; ++j) {
      f32x4 z = {0.0f, 0.0f, 0.0f, 0.0f};
      acc[i][j] = z;
    }

  for (int kt = 0; kt < NKT; ++kt) {
    const int kb = kt * 128;   // byte advance along K
    #pragma unroll
    for (int c = 0; c < 4; ++c) {
      gload16(gA + c * (8 * DIN * 2) + kb, ldsA + c * 1024);
      gload16(gB + c * (8 * DIN * 2) + kb, ldsB + c * 1024);
    }
    __syncthreads();   // compiler emits vmcnt(0) drain before barrier

    #pragma unroll
    for (int kh = 0; kh < 2; ++kh) {
      s16x8 aq[4], bq[4];
      #pragma unroll
      for (int mf = 0; mf < 4; ++mf) {
        const int row = wr * 64 + mf * 16 + (lane & 15);
        int byte_ = (row << 7) + ((kh * 32 + (lane >> 4) * 8) << 1);
        byte_ ^= (row & 7) << 4;
        aq[mf] = *(s16x8*)(&smem[byte_]);
      }
      #pragma unroll
      for (int nf = 0; nf < 4; ++nf) {
        const int row = wc * 64 + nf * 16 + (lane & 15);
        int byte_ = 16384 + (row << 7) + ((kh * 32 + (lane >> 4) * 8) << 1);
        byte_ ^= (row & 7) << 4;
        bq[nf] = *(s16x8*)(&smem[byte_]);
      }
      #pragma unroll
      for (int mf = 0; mf < 4; ++mf)
        #pragma unroll
        for (int nf = 0; nf < 4; ++nf)
          acc[mf][nf] = __builtin_amdgcn_mfma_f32_16x16x32_bf16(aq[mf], bq[nf], acc[mf][nf], 0, 0, 0);
    }
    __syncthreads();
  }

  // ---- fused epilogue: acc -> LDS -> gate math -> new_hidden, new_state
  float* creg = (float*)smem + wid * 2048;   // [32][64] f32 per wave
  const int mbase = mt * 128 + wr * 64;
  const int hbase = nt * 32 + wc * 16;
  const int bcol  = nt * 128 + wc * 64;
  #pragma unroll
  for (int p = 0; p < 2; ++p) {
    #pragma unroll
    for (int mf = 0; mf < 2; ++mf) {
      #pragma unroll
      for (int nf = 0; nf < 4; ++nf) {
        const int lrow = mf * 16 + (lane >> 4) * 4;   // C/D: row=(lane>>4)*4+r
        const int lcol = nf * 16 + (lane & 15);       //      col=lane&15
        #pragma unroll
        for (int r = 0; r < 4; ++r)
          creg[(lrow + r) * 64 + lcol] = acc[p * 2 + mf][nf][r];
      }
    }
    #pragma unroll
    for (int j = 0; j < 8; ++j) {
      const int idx = lane + j * 64;
      const int row = idx >> 4;
      const int hc  = idx & 15;
      f32x4 g4 = *(f32x4*)(creg + row * 64 + hc * 4);
      f32x4 bb = *(const f32x4*)(b4 + bcol + hc * 4);
      const int m  = mbase + p * 32 + row;
      const int hg = hbase + hc;
      const float ig = sigmoidf_(g4.x + bb.x);
      const float fg = sigmoidf_(g4.y + bb.y);
      const float og = sigmoidf_(g4.z + bb.z);
      const float cg = tanhf_(g4.w + bb.w);
      const float ns = fg * OLD[m * HD + hg] + ig * cg;
      const float nh = og * tanhf_(ns);
      out[m * HD + hg] = nh;
      out[BS * HD + m * HD + hg] = ns;
    }
  }
}

extern "C" void kernel_launch(void* const* d_in, const int* in_sizes, int n_in,
                              void* d_out, int out_size, void* d_ws, size_t ws_size,
                              hipStream_t stream) {
  const float* X   = (const float*)d_in[0];
  const float* PT  = (const float*)d_in[1];
  const float* PL  = (const float*)d_in[2];
  const float* OLD = (const float*)d_in[3];
  const float* Wi  = (const float*)d_in[4];
  const float* bi  = (const float*)d_in[5];
  const float* Wf  = (const float*)d_in[6];
  const float* bfv = (const float*)d_in[7];
  const float* Wo  = (const float*)d_in[8];
  const float* bo  = (const float*)d_in[9];
  const float* Ws  = (const float*)d_in[10];
  const float* bsv = (const float*)d_in[11];
  float* out = (float*)d_out;

  unsigned short* Wt  = (unsigned short*)d_ws;                              // 2.62 MB
  float*          b4  = (float*)((char*)d_ws + (size_t)N4 * DIN * 2);       // 4 KB
  unsigned short* Abf = (unsigned short*)((char*)d_ws + (size_t)N4 * DIN * 2 + 4096);  // 41.9 MB

  conv_w_kernel<<<N4, 256, 0, stream>>>(Wi, bi, Wf, bfv, Wo, bo, Ws, bsv, Wt, b4);
  conv_a_kernel<<<(BS * (DIN / 8)) / 256, 256, 0, stream>>>(X, PT, PL, Abf);
  lstm_gemm_kernel<<<(BS / 128) * 8, 256, 0, stream>>>(Abf, Wt, b4, OLD, out);
}

// Round 3
// 78.364 us; speedup vs baseline: 1.6679x; 1.0497x over previous
//
#include <hip/hip_runtime.h>
#include <stdint.h>

#define BS   16384
#define XRW  768
#define HD   256
#define DIN  1280
#define N4   1024
#define NKT  20   // 1280 / 64 K-tiles

typedef __attribute__((ext_vector_type(4))) float f32x4;
typedef __attribute__((ext_vector_type(8))) short s16x8;

__device__ __forceinline__ unsigned short f2bf(float f) {
  uint32_t u = __builtin_bit_cast(uint32_t, f);
  u += 0x7FFFu + ((u >> 16) & 1u);   // RNE
  return (unsigned short)(u >> 16);
}
__device__ __forceinline__ float sigmoidf_(float x) {
  return 1.0f / (1.0f + __expf(-x));
}
__device__ __forceinline__ float tanhf_(float x) {
  return 1.0f - 2.0f / (__expf(2.0f * x) + 1.0f);
}
__device__ __forceinline__ void gload16(const void* g, void* l) {
  __builtin_amdgcn_global_load_lds((const __attribute__((address_space(1))) void*)g,
                                   (__attribute__((address_space(3))) void*)l, 16, 0, 0);
}

// ---- Wt[n'][k] bf16 row-major, n' = h*4 + gate; b4[n'].
__global__ void conv_w_kernel(const float* __restrict__ Wi, const float* __restrict__ bi,
                              const float* __restrict__ Wf, const float* __restrict__ bfv,
                              const float* __restrict__ Wo, const float* __restrict__ bo,
                              const float* __restrict__ Ws, const float* __restrict__ bsv,
                              unsigned short* __restrict__ Wt, float* __restrict__ b4) {
  const int np = blockIdx.x;
  const int h = np >> 2, g = np & 3;
  const float* W  = (g == 0) ? Wi : (g == 1) ? Wf : (g == 2) ? Wo : Ws;
  const float* bb = (g == 0) ? bi : (g == 1) ? bfv : (g == 2) ? bo : bsv;
  if (threadIdx.x == 0) b4[np] = bb[h];
  for (int k = threadIdx.x; k < DIN; k += 256)
    Wt[np * DIN + k] = f2bf(W[k * HD + h]);
}

// ---- Abf[m][k] bf16 row-major = concat(x, pt, pl). Memory-bound.
__global__ __launch_bounds__(256) void conv_a_kernel(const float* __restrict__ X,
                                                     const float* __restrict__ PT,
                                                     const float* __restrict__ PL,
                                                     unsigned short* __restrict__ Abf) {
  const int idx = blockIdx.x * 256 + threadIdx.x;   // [0, 16384*160)
  const int m = idx / 160;
  const int c = idx - m * 160;
  const int k = c << 3;
  const float* src;
  if (k < XRW)           src = X  + (size_t)m * XRW + k;
  else if (k < XRW + HD) src = PT + (size_t)m * HD + (k - XRW);
  else                   src = PL + (size_t)m * HD + (k - XRW - HD);
  f32x4 a = *(const f32x4*)src;
  f32x4 b = *(const f32x4*)(src + 4);
  s16x8 o;
  o[0] = (short)f2bf(a.x); o[1] = (short)f2bf(a.y);
  o[2] = (short)f2bf(a.z); o[3] = (short)f2bf(a.w);
  o[4] = (short)f2bf(b.x); o[5] = (short)f2bf(b.y);
  o[6] = (short)f2bf(b.z); o[7] = (short)f2bf(b.w);
  *(s16x8*)(Abf + (size_t)idx * 8) = o;
}

// ---- 256x256 tile, BK=64, 8 waves (2M x 4N, 128x64 each), counted-vmcnt pipeline.
// LDS: A [2][256][64] bf16 @ [0,64K), B same @ [64K,128K), XOR-swizzled
// (byte ^= (row&7)<<4) via pre-swizzled global source + swizzled ds_read.
__global__ __launch_bounds__(512, 2)
void lstm_gemm_kernel(const unsigned short* __restrict__ Abf,
                      const unsigned short* __restrict__ Wt,
                      const float* __restrict__ b4,
                      const float* __restrict__ OLD,
                      float* __restrict__ out) {
  __shared__ unsigned char smem[131072];
  const int tid  = threadIdx.x;
  const int wid  = tid >> 6;
  const int lane = tid & 63;

  // T1: each XCD owns 8 contiguous M-panels x all 4 N-tiles (grid=256, 1 blk/CU)
  const int H = blockIdx.x;
  const int xcd = H & 7, slot = H >> 3;          // slot in [0,32)
  const int mt = xcd * 8 + (slot >> 2);          // [0,64)
  const int nt = slot & 3;                       // [0,4)
  const int wr = wid >> 2, wc = wid & 3;

  // ---- staging: per K-tile, A = 4 issues (rows c*64 + tid>>3), B same.
  // LDS linear dest; global source col pre-swizzled (loop-invariant per lane).
  const int r8   = lane >> 3;
  const int scol = ((lane & 7) ^ r8) << 4;
  const char* gA = (const char*)Abf + (size_t)(mt * 256 + wid * 8 + r8) * (DIN * 2) + scol;
  const char* gB = (const char*)Wt  + (size_t)(nt * 256 + wid * 8 + r8) * (DIN * 2) + scol;

#define STAGE(kk, buf) do {                                                        \
    const int kb_ = (kk) * 128;                                                    \
    _Pragma("unroll")                                                              \
    for (int c_ = 0; c_ < 4; ++c_) {                                               \
      gload16(gA + (size_t)c_ * (64 * DIN * 2) + kb_,                              \
              &smem[(buf) * 32768 + c_ * 8192 + wid * 1024]);                      \
      gload16(gB + (size_t)c_ * (64 * DIN * 2) + kb_,                              \
              &smem[65536 + (buf) * 32768 + c_ * 8192 + wid * 1024]);              \
    }                                                                              \
  } while (0)

  // ---- ds_read fragment addressing (per-lane invariants)
  const int rx   = lane & 15;
  const int axor = (lane & 7) << 4;
  const int col0 = (((lane >> 4) * 16)) ^ axor;        // kh=0
  const int col1 = ((64 + (lane >> 4) * 16)) ^ axor;   // kh=1
  const int aRow = (wr * 128 + rx) * 128;              // + mf*2048
  const int bRow = 65536 + (wc * 64 + rx) * 128;       // + nf*2048

  f32x4 acc[8][4];
  #pragma unroll
  for (int i = 0; i < 8; ++i)
    #pragma unroll
    for (int j = 0; j < 4; ++j) {
      f32x4 z = {0.0f, 0.0f, 0.0f, 0.0f};
      acc[i][j] = z;
    }

#define FRAGS(kh_col, buf) do {                                                    \
    const int bo_ = (buf) * 32768;                                                 \
    _Pragma("unroll")                                                              \
    for (int mf = 0; mf < 8; ++mf)                                                 \
      aq[mf] = *(s16x8*)(&smem[bo_ + aRow + mf * 2048 + (kh_col)]);                \
    _Pragma("unroll")                                                              \
    for (int nf = 0; nf < 4; ++nf)                                                 \
      bq[nf] = *(s16x8*)(&smem[bo_ + bRow + nf * 2048 + (kh_col)]);                \
  } while (0)

#define MFMAS() do {                                                               \
    __builtin_amdgcn_s_setprio(1);                                                 \
    _Pragma("unroll")                                                              \
    for (int mf = 0; mf < 8; ++mf)                                                 \
      _Pragma("unroll")                                                            \
      for (int nf = 0; nf < 4; ++nf)                                               \
        acc[mf][nf] = __builtin_amdgcn_mfma_f32_16x16x32_bf16(aq[mf], bq[nf],      \
                                                              acc[mf][nf], 0, 0, 0);\
    __builtin_amdgcn_s_setprio(0);                                                 \
  } while (0)

  STAGE(0, 0);
  STAGE(1, 1);

  for (int k = 0; k < NKT - 1; ++k) {
    const int buf = k & 1;
    s16x8 aq[8], bq[4];
    asm volatile("s_waitcnt vmcnt(8)" ::: "memory");   // tile k landed; k+1 in flight
    __builtin_amdgcn_s_barrier();
    FRAGS(col0, buf);
    MFMAS();
    FRAGS(col1, buf);
    asm volatile("s_waitcnt lgkmcnt(0)" ::: "memory"); // my reads of buf done
    __builtin_amdgcn_sched_barrier(0);
    __builtin_amdgcn_s_barrier();                      // all waves' reads done
    if (k + 2 < NKT) {
      STAGE(k + 2, buf);                               // overwrite buf, overlaps MFMAs
      __builtin_amdgcn_sched_barrier(0);               // keep issue before MFMA block
    }
    MFMAS();
  }
  {  // peeled last K-tile
    const int buf = (NKT - 1) & 1;
    s16x8 aq[8], bq[4];
    asm volatile("s_waitcnt vmcnt(0)" ::: "memory");
    __builtin_amdgcn_s_barrier();
    FRAGS(col0, buf);
    MFMAS();
    FRAGS(col1, buf);
    MFMAS();
  }

  // ---- fused epilogue: acc -> LDS (8KB/wave) -> gates -> new_hidden,new_state
  __syncthreads();
  float* creg = (float*)smem + wid * 2048;   // [32][64] f32 per wave
  const int mbase = mt * 256 + wr * 128;
  const int hbase = nt * 64 + wc * 16;
  const int bcol  = nt * 256 + wc * 64;
  #pragma unroll
  for (int p = 0; p < 4; ++p) {
    #pragma unroll
    for (int mf2 = 0; mf2 < 2; ++mf2) {
      #pragma unroll
      for (int nf = 0; nf < 4; ++nf) {
        const int lrow = mf2 * 16 + (lane >> 4) * 4;   // C/D: row=(lane>>4)*4+r
        const int lcol = nf * 16 + (lane & 15);        //      col=lane&15
        #pragma unroll
        for (int r = 0; r < 4; ++r)
          creg[(lrow + r) * 64 + lcol] = acc[p * 2 + mf2][nf][r];
      }
    }
    #pragma unroll
    for (int j = 0; j < 8; ++j) {
      const int idx = lane + j * 64;
      const int row = idx >> 4;
      const int hc  = idx & 15;
      f32x4 g4 = *(f32x4*)(creg + row * 64 + hc * 4);
      f32x4 bb = *(const f32x4*)(b4 + bcol + hc * 4);
      const int m  = mbase + p * 32 + row;
      const int hg = hbase + hc;
      const float ig = sigmoidf_(g4.x + bb.x);
      const float fg = sigmoidf_(g4.y + bb.y);
      const float og = sigmoidf_(g4.z + bb.z);
      const float cg = tanhf_(g4.w + bb.w);
      const float ns = fg * OLD[m * HD + hg] + ig * cg;
      const float nh = og * tanhf_(ns);
      out[m * HD + hg] = nh;
      out[BS * HD + m * HD + hg] = ns;
    }
  }
#undef STAGE
#undef FRAGS
#undef MFMAS
}

extern "C" void kernel_launch(void* const* d_in, const int* in_sizes, int n_in,
                              void* d_out, int out_size, void* d_ws, size_t ws_size,
                              hipStream_t stream) {
  const float* X   = (const float*)d_in[0];
  const float* PT  = (const float*)d_in[1];
  const float* PL  = (const float*)d_in[2];
  const float* OLD = (const float*)d_in[3];
  const float* Wi  = (const float*)d_in[4];
  const float* bi  = (const float*)d_in[5];
  const float* Wf  = (const float*)d_in[6];
  const float* bfv = (const float*)d_in[7];
  const float* Wo  = (const float*)d_in[8];
  const float* bo  = (const float*)d_in[9];
  const float* Ws  = (const float*)d_in[10];
  const float* bsv = (const float*)d_in[11];
  float* out = (float*)d_out;

  unsigned short* Wt  = (unsigned short*)d_ws;                              // 2.62 MB
  float*          b4  = (float*)((char*)d_ws + (size_t)N4 * DIN * 2);       // 4 KB
  unsigned short* Abf = (unsigned short*)((char*)d_ws + (size_t)N4 * DIN * 2 + 4096);  // 41.9 MB

  conv_w_kernel<<<N4, 256, 0, stream>>>(Wi, bi, Wf, bfv, Wo, bo, Ws, bsv, Wt, b4);
  conv_a_kernel<<<(BS * (DIN / 8)) / 256, 256, 0, stream>>>(X, PT, PL, Abf);
  lstm_gemm_kernel<<<256, 512, 0, stream>>>(Abf, Wt, b4, OLD, out);
}